// Round 8
// baseline (73.265 us; speedup 1.0000x reference)
//
#include <hip/hip_runtime.h>

#define NCLS 21
#define HW   (512 * 512)            // pixels per plane (2^18)
#define NB   16                     // batch
#define NPIX (NB * HW)              // 4,194,304 pixels
#define BLK  1024
#define SEG  8192                   // pixels per block: 2 chunks x 4096
#define CHUNK 4096                  // pixels per chunk (BLK * 4)
#define GRID (NPIX / SEG)           // 512 blocks, exact

typedef float v4f __attribute__((ext_vector_type(4)));
typedef int   v4i __attribute__((ext_vector_type(4)));

// Single fused kernel, round-7 memory structure + fence-FREE ticket finalize.
// cnt layout: [0..20] inter, [21..41] cp, [42..62] cg, [63] ticket.
// Ordering argument (no __threadfence — round 6 showed an agent-scope fence
// emits per-wave L2 writebacks and cost 3x): all cross-block communication is
// device-scope atomic RMWs, which complete at the coherent point. The
// compiler's full vmcnt(0) drain at __syncthreads() guarantees each block's
// counter RMWs have COMPLETED before its ticket RMW issues, so observing
// ticket==GRID-1 implies all 512 blocks' counter atomics have landed.
__global__ void __launch_bounds__(BLK) iou_kernel(
    const float* __restrict__ pred, const int* __restrict__ gt,
    unsigned int* __restrict__ cnt, float* __restrict__ out) {

    __shared__ unsigned int h[3 * NCLS];
    __shared__ unsigned int ticket;
    for (int i = threadIdx.x; i < 3 * NCLS; i += BLK) h[i] = 0u;
    __syncthreads();

    const int p0 = blockIdx.x * SEG + threadIdx.x * 4;  // chunk A first pixel
    // SEG (8192) divides HW (2^18), so chunks A and B sit in the same image.
    const int b  = p0 >> 18;                            // p0 / HW
    const int hw = p0 & (HW - 1);                       // p0 % HW
    const float* base = pred + (size_t)b * (NCLS * HW) + hw;

    v4f mA = *(const v4f*)base;
    v4f mB = *(const v4f*)(base + CHUNK);
    int a0 = 0, a1 = 0, a2 = 0, a3 = 0;
    int b0 = 0, b1 = 0, b2 = 0, b3 = 0;
#pragma unroll
    for (int c = 1; c < NCLS; ++c) {
        const float* pc = base + (size_t)c * HW;
        const v4f xA = *(const v4f*)pc;
        const v4f xB = *(const v4f*)(pc + CHUNK);
        // strict > keeps first max (jnp argmax tie-break)
        if (xA.x > mA.x) { mA.x = xA.x; a0 = c; }
        if (xA.y > mA.y) { mA.y = xA.y; a1 = c; }
        if (xA.z > mA.z) { mA.z = xA.z; a2 = c; }
        if (xA.w > mA.w) { mA.w = xA.w; a3 = c; }
        if (xB.x > mB.x) { mB.x = xB.x; b0 = c; }
        if (xB.y > mB.y) { mB.y = xB.y; b1 = c; }
        if (xB.z > mB.z) { mB.z = xB.z; b2 = c; }
        if (xB.w > mB.w) { mB.w = xB.w; b3 = c; }
    }
    const v4i gA = *(const v4i*)(gt + p0);
    const v4i gB = *(const v4i*)(gt + p0 + CHUNK);

    atomicAdd(&h[NCLS + a0], 1u);
    atomicAdd(&h[NCLS + a1], 1u);
    atomicAdd(&h[NCLS + a2], 1u);
    atomicAdd(&h[NCLS + a3], 1u);
    atomicAdd(&h[NCLS + b0], 1u);
    atomicAdd(&h[NCLS + b1], 1u);
    atomicAdd(&h[NCLS + b2], 1u);
    atomicAdd(&h[NCLS + b3], 1u);
    atomicAdd(&h[2 * NCLS + gA.x], 1u);
    atomicAdd(&h[2 * NCLS + gA.y], 1u);
    atomicAdd(&h[2 * NCLS + gA.z], 1u);
    atomicAdd(&h[2 * NCLS + gA.w], 1u);
    atomicAdd(&h[2 * NCLS + gB.x], 1u);
    atomicAdd(&h[2 * NCLS + gB.y], 1u);
    atomicAdd(&h[2 * NCLS + gB.z], 1u);
    atomicAdd(&h[2 * NCLS + gB.w], 1u);
    if (a0 == gA.x) atomicAdd(&h[a0], 1u);
    if (a1 == gA.y) atomicAdd(&h[a1], 1u);
    if (a2 == gA.z) atomicAdd(&h[a2], 1u);
    if (a3 == gA.w) atomicAdd(&h[a3], 1u);
    if (b0 == gB.x) atomicAdd(&h[b0], 1u);
    if (b1 == gB.y) atomicAdd(&h[b1], 1u);
    if (b2 == gB.z) atomicAdd(&h[b2], 1u);
    if (b3 == gB.w) atomicAdd(&h[b3], 1u);

    __syncthreads();
    for (int i = threadIdx.x; i < 3 * NCLS; i += BLK) {
        unsigned int val = h[i];
        if (val) atomicAdd(&cnt[i], val);   // device-scope RMW (G12)
    }
    // __syncthreads() drains vmcnt(0) per wave: all this block's counter
    // RMWs have completed at the coherent point before the ticket issues.
    __syncthreads();

    if (threadIdx.x == 0) ticket = atomicAdd(&cnt[63], 1u);
    __syncthreads();

    if (ticket == GRID - 1) {               // last block finalizes
        __shared__ float sIou[NCLS];
        if (threadIdx.x < NCLS) {
            // atomic RMW reads give a coherent cross-XCD view (G16)
            const float inter = (float)atomicOr(&cnt[threadIdx.x], 0u);
            const float cp    = (float)atomicOr(&cnt[NCLS + threadIdx.x], 0u);
            const float cg    = (float)atomicOr(&cnt[2 * NCLS + threadIdx.x], 0u);
            const float uni   = cp + cg - inter;
            sIou[threadIdx.x] =
                (inter > 0.0f) ? inter / (uni > 0.0f ? uni : 1.0f) : 0.0f;
        }
        __syncthreads();
        if (threadIdx.x == 0) {
            float s = 0.0f;
#pragma unroll
            for (int c = 0; c < NCLS; ++c) s += sIou[c];
            out[0] = s / (float)NCLS;
        }
    }
}

extern "C" void kernel_launch(void* const* d_in, const int* in_sizes, int n_in,
                              void* d_out, int out_size, void* d_ws, size_t ws_size,
                              hipStream_t stream) {
    const float*  pred = (const float*)d_in[0];
    const int*    gt   = (const int*)d_in[1];
    float*        out  = (float*)d_out;
    unsigned int* cnt  = (unsigned int*)d_ws;

    // d_ws is poisoned (0xAA) once and never re-poisoned: zero counters +
    // ticket (64 uints) every call.
    hipMemsetAsync(cnt, 0, 64 * sizeof(unsigned int), stream);

    iou_kernel<<<GRID, BLK, 0, stream>>>(pred, gt, cnt, out);
}

// Round 9
// 68.873 us; speedup vs baseline: 1.0638x; 1.0638x over previous
//
#include <hip/hip_runtime.h>

#define NCLS 21
#define HW   (512 * 512)            // pixels per plane (2^18)
#define NB   16                     // batch
#define NPIX (NB * HW)              // 4,194,304 pixels
#define BLK  1024
#define SEG  8192                   // pixels per block: 2 chunks x 4096
#define CHUNK 4096                  // pixels per chunk (BLK * 4)
#define GRID (NPIX / SEG)           // 512 blocks, exact
#define CSTRIDE 64                  // per-block slot stride in cnt (63 used)

typedef float v4f __attribute__((ext_vector_type(4)));
typedef int   v4i __attribute__((ext_vector_type(4)));

// Phase 1: per-pixel argmax over 21 classes + LDS histograms.
// Tail: PLAIN per-block partial stores (no device atomics, no memset needed;
// cross-kernel visibility via the standard dispatch-boundary release/acquire).
// Partial layout: cnt[block*64 + 0..20]=inter, [21..41]=cp, [42..62]=cg.
__global__ void __launch_bounds__(BLK) iou_hist_kernel(
    const float* __restrict__ pred, const int* __restrict__ gt,
    unsigned int* __restrict__ cnt) {
    __shared__ unsigned int h[3 * NCLS];
    for (int i = threadIdx.x; i < 3 * NCLS; i += BLK) h[i] = 0u;
    __syncthreads();

    const int p0 = blockIdx.x * SEG + threadIdx.x * 4;  // chunk A first pixel
    // SEG (8192) divides HW (2^18), so chunks A and B sit in the same image.
    const int b  = p0 >> 18;                            // p0 / HW
    const int hw = p0 & (HW - 1);                       // p0 % HW
    const float* base = pred + (size_t)b * (NCLS * HW) + hw;

    v4f mA = *(const v4f*)base;
    v4f mB = *(const v4f*)(base + CHUNK);
    int a0 = 0, a1 = 0, a2 = 0, a3 = 0;
    int b0 = 0, b1 = 0, b2 = 0, b3 = 0;
#pragma unroll
    for (int c = 1; c < NCLS; ++c) {
        const float* pc = base + (size_t)c * HW;
        const v4f xA = *(const v4f*)pc;
        const v4f xB = *(const v4f*)(pc + CHUNK);
        // strict > keeps first max (jnp argmax tie-break)
        if (xA.x > mA.x) { mA.x = xA.x; a0 = c; }
        if (xA.y > mA.y) { mA.y = xA.y; a1 = c; }
        if (xA.z > mA.z) { mA.z = xA.z; a2 = c; }
        if (xA.w > mA.w) { mA.w = xA.w; a3 = c; }
        if (xB.x > mB.x) { mB.x = xB.x; b0 = c; }
        if (xB.y > mB.y) { mB.y = xB.y; b1 = c; }
        if (xB.z > mB.z) { mB.z = xB.z; b2 = c; }
        if (xB.w > mB.w) { mB.w = xB.w; b3 = c; }
    }
    const v4i gA = *(const v4i*)(gt + p0);
    const v4i gB = *(const v4i*)(gt + p0 + CHUNK);

    atomicAdd(&h[NCLS + a0], 1u);
    atomicAdd(&h[NCLS + a1], 1u);
    atomicAdd(&h[NCLS + a2], 1u);
    atomicAdd(&h[NCLS + a3], 1u);
    atomicAdd(&h[NCLS + b0], 1u);
    atomicAdd(&h[NCLS + b1], 1u);
    atomicAdd(&h[NCLS + b2], 1u);
    atomicAdd(&h[NCLS + b3], 1u);
    atomicAdd(&h[2 * NCLS + gA.x], 1u);
    atomicAdd(&h[2 * NCLS + gA.y], 1u);
    atomicAdd(&h[2 * NCLS + gA.z], 1u);
    atomicAdd(&h[2 * NCLS + gA.w], 1u);
    atomicAdd(&h[2 * NCLS + gB.x], 1u);
    atomicAdd(&h[2 * NCLS + gB.y], 1u);
    atomicAdd(&h[2 * NCLS + gB.z], 1u);
    atomicAdd(&h[2 * NCLS + gB.w], 1u);
    if (a0 == gA.x) atomicAdd(&h[a0], 1u);
    if (a1 == gA.y) atomicAdd(&h[a1], 1u);
    if (a2 == gA.z) atomicAdd(&h[a2], 1u);
    if (a3 == gA.w) atomicAdd(&h[a3], 1u);
    if (b0 == gB.x) atomicAdd(&h[b0], 1u);
    if (b1 == gB.y) atomicAdd(&h[b1], 1u);
    if (b2 == gB.z) atomicAdd(&h[b2], 1u);
    if (b3 == gB.w) atomicAdd(&h[b3], 1u);

    __syncthreads();
    unsigned int* myout = cnt + (size_t)blockIdx.x * CSTRIDE;
    for (int i = threadIdx.x; i < 3 * NCLS; i += BLK)
        myout[i] = h[i];                    // plain store: per-block partial
}

// Phase 2: one block sums 512 partial histograms, then computes mean IoU.
__global__ void __launch_bounds__(1024) iou_final_kernel(
    const unsigned int* __restrict__ cnt, float* __restrict__ out) {
    __shared__ unsigned int tot[3 * NCLS];
    if (threadIdx.x < 3 * NCLS) tot[threadIdx.x] = 0u;
    __syncthreads();

    // 16 groups of 64 threads; group g sums blocks [32g, 32g+32).
    const int slot = threadIdx.x & 63;      // counter index (63 unused)
    const int g    = threadIdx.x >> 6;
    if (slot < 3 * NCLS) {
        unsigned int s = 0;
        const int blk0 = g * (GRID / 16);
#pragma unroll 4
        for (int kb = blk0; kb < blk0 + GRID / 16; ++kb)
            s += cnt[(size_t)kb * CSTRIDE + slot];   // coalesced across slot
        atomicAdd(&tot[slot], s);
    }
    __syncthreads();

    float iou = 0.0f;
    if (threadIdx.x < NCLS) {
        const float inter = (float)tot[threadIdx.x];
        const float cp    = (float)tot[NCLS + threadIdx.x];
        const float cg    = (float)tot[2 * NCLS + threadIdx.x];
        const float uni   = cp + cg - inter;
        iou = (inter > 0.0f) ? inter / (uni > 0.0f ? uni : 1.0f) : 0.0f;
    }
#pragma unroll
    for (int off = 32; off >= 1; off >>= 1)
        iou += __shfl_down(iou, off, 64);   // wave 0 reduces lanes 0..20
    if (threadIdx.x == 0) out[0] = iou / (float)NCLS;
}

extern "C" void kernel_launch(void* const* d_in, const int* in_sizes, int n_in,
                              void* d_out, int out_size, void* d_ws, size_t ws_size,
                              hipStream_t stream) {
    const float*  pred = (const float*)d_in[0];
    const int*    gt   = (const int*)d_in[1];
    float*        out  = (float*)d_out;
    unsigned int* cnt  = (unsigned int*)d_ws;   // needs GRID*64*4 = 128 KB

    // No memset needed: every slot read by the final kernel is written
    // unconditionally by the hist kernel each call (poison-safe).
    iou_hist_kernel<<<GRID, BLK, 0, stream>>>(pred, gt, cnt);
    iou_final_kernel<<<1, 1024, 0, stream>>>(cnt, out);
}